// Round 12
// baseline (222.205 us; speedup 1.0000x reference)
//
#include <hip/hip_runtime.h>
#include <hip/hip_bf16.h>

// MHA forward, MI355X/gfx950.
// cast->bf16, fused QKV proj (R7-measured BK=32 NT-GEMM, Q cols pre-scaled),
// causal flash attention (K in registers from L2 single-buffered in-place,
// V dbuf LDS, 1 barrier/tile), out proj (R7-measured config).

#define DEVI __device__ __forceinline__

typedef __attribute__((ext_vector_type(4))) float f32x4;
typedef __attribute__((ext_vector_type(8))) short s16x8;

static constexpr int SEQ = 2048;
static constexpr int DM  = 1024;
static constexpr int NH  = 16;
static constexpr int HD  = 64;
static constexpr int LDQKV = 3072;   // fused QKV row stride

DEVI short f2bf(float f) {
  __hip_bfloat16 h = __float2bfloat16(f);
  return *(short*)&h;
}

// ---------------- fp32 -> bf16 casts ----------------
__global__ void cast_kernel(const float* __restrict__ in, short* __restrict__ out, int n4) {
  int i = blockIdx.x * blockDim.x + threadIdx.x;
  if (i >= n4) return;
  float4 v = ((const float4*)in)[i];
  short4 o;
  o.x = f2bf(v.x); o.y = f2bf(v.y); o.z = f2bf(v.z); o.w = f2bf(v.w);
  ((short4*)out)[i] = o;
}

// 4 weight matrices, 1M floats (256K float4) each. seg = blockIdx>>10.
__global__ void cast4_kernel(const float* __restrict__ w0, const float* __restrict__ w1,
                             const float* __restrict__ w2, const float* __restrict__ w3,
                             short* __restrict__ o012, short* __restrict__ o3) {
  int seg = blockIdx.x >> 10;
  int i = (blockIdx.x & 1023) * blockDim.x + threadIdx.x;   // 0..256K-1 (float4 idx)
  const float* src = (seg == 0) ? w0 : (seg == 1) ? w1 : (seg == 2) ? w2 : w3;
  short* dst = (seg == 3) ? o3 : (o012 + (size_t)seg * (1u << 20));
  float4 v = ((const float4*)src)[i];
  short4 o;
  o.x = f2bf(v.x); o.y = f2bf(v.y); o.z = f2bf(v.z); o.w = f2bf(v.w);
  ((short4*)dst)[i] = o;
}

// ---------------- NT GEMM (R7-measured config): C = A * B^T ----------------
// A: M x K bf16 row-major, B: N x K bf16 row-major. 128x128 tile, BK=32,
// 4 waves each computing a 64x64 quadrant (4x4 frags of 16x16x32 MFMA).
// m97 structure: global_load_lds width-16 staging, 2 barriers/K-step.
// Columns < qcols get scaled by qscale in the epilogue.
template<bool BF16_OUT>
__global__ __launch_bounds__(256) void gemm_nt(const short* __restrict__ A,
                                               const short* __restrict__ Bm,
                                               void* __restrict__ Cv,
                                               int M, int N, int K,
                                               int qcols, float qscale) {
  __shared__ short As[128 * 32];
  __shared__ short Bs[128 * 32];
  const int t = threadIdx.x;
  const int l = t & 63;
  const int w = t >> 6;
  const int wr = w >> 1, wc = w & 1;
  const int lr = l & 15, lg = l >> 4;
  const int m0 = blockIdx.y * 128, n0 = blockIdx.x * 128;
  f32x4 acc[4][4] = {};

  for (int k0 = 0; k0 < K; k0 += 32) {
    __syncthreads();  // previous iteration's LDS reads done
#pragma unroll
    for (int i = 0; i < 2; ++i) {
      int idx = t * 8 + i * 2048;     // flat bf16 element index into 128x32 tile
      int row = idx >> 5, col = idx & 31;
      __builtin_amdgcn_global_load_lds(
          (const __attribute__((address_space(1))) void*)(A + (size_t)(m0 + row) * K + k0 + col),
          (__attribute__((address_space(3))) void*)(As + idx), 16, 0, 0);
      __builtin_amdgcn_global_load_lds(
          (const __attribute__((address_space(1))) void*)(Bm + (size_t)(n0 + row) * K + k0 + col),
          (__attribute__((address_space(3))) void*)(Bs + idx), 16, 0, 0);
    }
    __syncthreads();  // staged (compiler drains vmcnt before barrier)

    s16x8 af[4], bfr[4];
#pragma unroll
    for (int i = 0; i < 4; ++i)
      af[i] = *(const s16x8*)&As[(wr * 64 + i * 16 + lr) * 32 + lg * 8];
#pragma unroll
    for (int j = 0; j < 4; ++j)
      bfr[j] = *(const s16x8*)&Bs[(wc * 64 + j * 16 + lr) * 32 + lg * 8];
#pragma unroll
    for (int i = 0; i < 4; ++i)
#pragma unroll
      for (int j = 0; j < 4; ++j)
        acc[i][j] = __builtin_amdgcn_mfma_f32_16x16x32_bf16(af[i], bfr[j], acc[i][j], 0, 0, 0);
  }

  const float s = (n0 < qcols) ? qscale : 1.0f;
  // epilogue: D[row=(l>>4)*4+r][col=l&15] per frag
#pragma unroll
  for (int i = 0; i < 4; ++i)
#pragma unroll
    for (int j = 0; j < 4; ++j)
#pragma unroll
      for (int r = 0; r < 4; ++r) {
        int row = m0 + wr * 64 + i * 16 + lg * 4 + r;
        int col = n0 + wc * 64 + j * 16 + lr;
        if constexpr (BF16_OUT)
          ((short*)Cv)[(size_t)row * N + col] = f2bf(acc[i][j][r] * s);
        else
          ((float*)Cv)[(size_t)row * N + col] = acc[i][j][r] * s;
      }
}

// ---------------- causal flash attention (K-in-registers) ----------------
// QKV: [B*S, 3072] bf16 (Q pre-scaled by 1/sqrt(hd)*log2(e); K at +1024, V at +2048).
// O: [B*S, 1024] bf16.
// 128-row q-tiles, 8 waves x 16 q-rows, 512 threads, 512 blocks @ 2/CU
// (enforced: __launch_bounds__(512,4) caps VGPR at 128; single-buffered K
// fragments keep demand ~115).
// Exact balance: bh = bid&31 (fast), g=(bid>>5)&7, rr=(bid>>8)&1, qt = rr?15-g:g
// -> each CU's 2 co-resident blocks total exactly 34 kv-tiles. (bh,qt) bijective.
// K fragments live in REGISTERS (global->reg, L2-resident) — removes the
// 16x-redundant per-wave K LDS reads that made the LDS pipe ~89% busy (R10 PMC).
// kf reloaded IN PLACE for tile kt+1 right after QK^T(kt) consumes it; the
// L2 latency hides under softmax+Ps+barrier+PV (>=600 cyc).
// V double-buffered in LDS -> ONE barrier per tile: write Vt[p]; V prefetch;
// QK^T (regs only); kf reload; softmax; Ps writes (intra-wave); lgkmcnt(0);
// s_barrier; PV. WAR on Vt[p]: separated by the intervening barrier (PV reads
// are MFMA-consumed before any wave reaches the next barrier).
__global__ __launch_bounds__(512, 4) void attn_kernel(const unsigned short* __restrict__ QKV,
                                                      unsigned short* __restrict__ O) {
  __shared__ short Vt[2][64 * 72];   // transposed: Vt[p][d][kv]
  __shared__ short Ps[128 * 72];

  const int t = threadIdx.x, l = t & 63, w = t >> 6;   // w: 0..7
  const int lr = l & 15, lg = l >> 4;
  const int bid = blockIdx.x;
  const int bh = bid & 31;              // fast dim: b*NH+h
  const int g  = (bid >> 5) & 7;
  const int rr = (bid >> 8) & 1;
  const int qt = rr ? 15 - g : g;       // q-tile 0..15 (128 rows each)
  const int b = bh >> 4, h = bh & 15;
  const int q0 = qt * 128;
  const int ktmax = 2 * qt + 1;         // kv tiles 0..ktmax (count 2qt+2, even)
  const size_t rowbase = (size_t)b * SEQ * LDQKV;
  const int cb = h * HD;

  // Q fragments: rows q0 + w*16 + lr, k-slices lg*8 (+32)
  s16x8 qf[2];
  {
    const unsigned short* qp = QKV + rowbase + cb + (size_t)(q0 + w * 16 + lr) * LDQKV + lg * 8;
    qf[0] = *(const s16x8*)(qp);
    qf[1] = *(const s16x8*)(qp + 32);
  }

  // per-lane global bases for K fragments and V staging
  const unsigned short* Kl = QKV + rowbase + DM + cb + (size_t)lr * LDQKV + lg * 8;
  const unsigned short* Vl = QKV + rowbase + 2 * DM + cb + (size_t)l * LDQKV + w * 8;

  f32x4 acc[4] = {};
  float mrun[4], lrun[4];   // lrun: per-lane partials (reduced in epilogue)
#pragma unroll
  for (int r = 0; r < 4; ++r) { mrun[r] = -3.0e38f; lrun[r] = 0.f; }

  // ---- prologue: load tile 0 (V staging reg + K fragments, single-buffered)
  s16x8 kf[2][4], vA, vB;
  vA = *(const s16x8*)(Vl);
#pragma unroll
  for (int dk = 0; dk < 2; ++dk)
#pragma unroll
    for (int j = 0; j < 4; ++j)
      kf[dk][j] = *(const s16x8*)(Kl + (size_t)(j * 16) * LDQKV + dk * 32);

  auto tile = [&](int kt, s16x8& vcur, s16x8& vnxt, int p) {
    const int kv0 = kt * 64;
    const int nkv = (kt < ktmax) ? kv0 + 64 : kv0;   // clamp on last iter

    // ---- write V staging reg to LDS buffer p (transposed)
#pragma unroll
    for (int jj = 0; jj < 8; ++jj) Vt[p][(w * 8 + jj) * 72 + l] = vcur[jj];

    // ---- T14 prefetch next V tile into the other staging reg
    vnxt = *(const s16x8*)(Vl + (size_t)nkv * LDQKV);

    // ---- S = Q K^T (registers only — no barrier needed)
    f32x4 sc[4] = {};
    __builtin_amdgcn_s_setprio(1);
#pragma unroll
    for (int dk = 0; dk < 2; ++dk)
#pragma unroll
      for (int j = 0; j < 4; ++j)
        sc[j] = __builtin_amdgcn_mfma_f32_16x16x32_bf16(qf[dk], kf[dk][j], sc[j], 0, 0, 0);
    __builtin_amdgcn_s_setprio(0);

    // ---- reload kf IN PLACE for tile kt+1 (issued now; consumed next tile;
    // L2 latency hides under softmax+Ps+barrier+PV)
#pragma unroll
    for (int dk = 0; dk < 2; ++dk)
#pragma unroll
      for (int j = 0; j < 4; ++j)
        kf[dk][j] = *(const s16x8*)(Kl + (size_t)(nkv + j * 16) * LDQKV + dk * 32);

    // ---- causal mask: only when this wave's rows intersect the diagonal
    if (kv0 + 63 > q0 + w * 16) {
#pragma unroll
      for (int j = 0; j < 4; ++j)
#pragma unroll
        for (int r = 0; r < 4; ++r) {
          int kg = kv0 + j * 16 + lr;
          int qg = q0 + w * 16 + lg * 4 + r;
          if (kg > qg) sc[j][r] = -3.0e38f;
        }
    }

    // ---- per-lane local maxima; full reduce + rescale only on demand (T13)
    float lmax[4];
#pragma unroll
    for (int r = 0; r < 4; ++r)
      lmax[r] = fmaxf(fmaxf(sc[0][r], sc[1][r]), fmaxf(sc[2][r], sc[3][r]));
    bool need = false;
#pragma unroll
    for (int r = 0; r < 4; ++r) need |= (lmax[r] > mrun[r] + 8.0f);
    if (__any(need)) {
#pragma unroll
      for (int r = 0; r < 4; ++r) {
        float m = lmax[r];
#pragma unroll
        for (int mk = 1; mk < 16; mk <<= 1) m = fmaxf(m, __shfl_xor(m, mk, 64));
        float mnew = fmaxf(mrun[r], m);
        float corr = exp2f(mrun[r] - mnew);
        mrun[r] = mnew;
        lrun[r] *= corr;
#pragma unroll
        for (int j = 0; j < 4; ++j) acc[j][r] *= corr;
      }
    }

    // ---- P = exp2(S - mrun); per-lane row-sum partials
#pragma unroll
    for (int r = 0; r < 4; ++r) {
      float rsum = 0.f;
#pragma unroll
      for (int j = 0; j < 4; ++j) {
        float p = exp2f(sc[j][r] - mrun[r]);
        sc[j][r] = p;
        rsum += p;
      }
      lrun[r] += rsum;
    }

    // ---- P -> LDS (intra-wave; wave w touches only rows [w*16, w*16+16))
#pragma unroll
    for (int j = 0; j < 4; ++j)
#pragma unroll
      for (int r = 0; r < 4; ++r)
        Ps[(w * 16 + lg * 4 + r) * 72 + j * 16 + lr] = f2bf(sc[j][r]);

    // ---- the tile's ONE barrier: all waves' Vt[p] (+own Ps) writes visible
    asm volatile("s_waitcnt lgkmcnt(0)" ::: "memory");
    __builtin_amdgcn_s_barrier();

    // ---- O += P @ V
    __builtin_amdgcn_s_setprio(1);
#pragma unroll
    for (int ks = 0; ks < 2; ++ks) {
      s16x8 pa = *(const s16x8*)&Ps[(w * 16 + lr) * 72 + ks * 32 + lg * 8];
#pragma unroll
      for (int j = 0; j < 4; ++j) {
        s16x8 vb = *(const s16x8*)&Vt[p][(j * 16 + lr) * 72 + ks * 32 + lg * 8];
        acc[j] = __builtin_amdgcn_mfma_f32_16x16x32_bf16(pa, vb, acc[j], 0, 0, 0);
      }
    }
    __builtin_amdgcn_s_setprio(0);
  };

  for (int kt = 0; kt <= ktmax; kt += 2) {
    tile(kt,     vA, vB, 0);
    tile(kt + 1, vB, vA, 1);
  }

  // ---- epilogue: reduce lrun across the 16 row-lanes, then O[q][d] = acc/lsum
#pragma unroll
  for (int r = 0; r < 4; ++r) {
    float ls = lrun[r];
#pragma unroll
    for (int mk = 1; mk < 16; mk <<= 1) ls += __shfl_xor(ls, mk, 64);
    lrun[r] = ls;
  }
#pragma unroll
  for (int j = 0; j < 4; ++j)
#pragma unroll
    for (int r = 0; r < 4; ++r) {
      int qg = q0 + w * 16 + lg * 4 + r;
      float o = acc[j][r] / lrun[r];
      O[(size_t)b * SEQ * DM + (size_t)qg * DM + cb + j * 16 + lr] = (unsigned short)f2bf(o);
    }
}

// ---------------- launch ----------------
extern "C" void kernel_launch(void* const* d_in, const int* in_sizes, int n_in,
                              void* d_out, int out_size, void* d_ws, size_t ws_size,
                              hipStream_t stream) {
  const float* x  = (const float*)d_in[0];
  const float* wq = (const float*)d_in[1];
  const float* wk = (const float*)d_in[2];
  const float* wv = (const float*)d_in[3];
  const float* wo = (const float*)d_in[4];
  float* out = (float*)d_out;

  short* ws   = (short*)d_ws;
  short* xb   = ws;                     // 4M elems  [4096,1024]
  short* wqkv = xb   + (4u << 20);      // 3M elems  [3072,1024] (wq;wk;wv)
  short* wob  = wqkv + (3u << 20);      // 1M elems  [1024,1024]
  short* QKV  = wob  + (1u << 20);      // 12M elems [4096,3072]
  short* Om   = QKV  + (12u << 20);     // 4M elems  [4096,1024]
  // total 24M shorts = 48 MB

  cast_kernel<<<4096, 256, 0, stream>>>(x, xb, 1 << 20);
  cast4_kernel<<<4096, 256, 0, stream>>>(wq, wk, wv, wo, wqkv, wob);

  // fused QKV projection; Q columns pre-scaled by 1/sqrt(hd)*log2(e)
  const float SCL = 0.125f * 1.4426950408889634f;
  gemm_nt<true><<<dim3(24, 32), 256, 0, stream>>>(xb, wqkv, QKV, 4096, LDQKV, 1024,
                                                  DM, SCL);

  // exact-balance 1D grid, 128-row q-tiles
  attn_kernel<<<512, 512, 0, stream>>>((const unsigned short*)QKV,
                                       (unsigned short*)Om);

  // output projection: [4096,1024] x [1024,1024]^T -> [4096,1024] fp32
  gemm_nt<false><<<dim3(8, 32), 256, 0, stream>>>(Om, wob, out, 4096, 1024, 1024,
                                                  0, 1.0f);
}